// Round 10
// baseline (1279.060 us; speedup 1.0000x reference)
//
#include <hip/hip_runtime.h>

// NGCF forward on gfx950 — round 16: break the fused-epilogue dep chain +
// fuse the bf16 shadow write into transform_self.
// R15 post-mortem: fusion netted -106us but spmm grew 147.5->169.5 — the
// t=fmaf(nk,W2,t) epilogue is a 64-deep serial FMA chain, only half-hidden
// at 80% occupancy. Fix: 4 independent accumulators (chain 64->16).
// refresh16 (2x ~15us + 2 launches) re-read cur just to emit bf16;
// transform_self holds the result in registers — emit cur16 there directly.

#define EMB 64

constexpr int kNUsers = 100000;
constexpr int kNItems = 50000;
constexpr int kNNodes = 150000;
constexpr int kNEdges = 4800000;
constexpr int kBatch  = 16384;
constexpr int kLayers = 3;
constexpr int kRngShift = 8;                     // 256 rows per range
constexpr int kNRanges  = (kNNodes + 255) >> 8;  // 586
constexpr int kEdgesPerBin = 16384;              // edges per bin block
constexpr int kBinBlocks = (kNEdges + kEdgesPerBin - 1) / kEdgesPerBin; // 293
constexpr int kEPW    = 16;                      // fallback only

__device__ __forceinline__ float f4c(const float4& v, int i) {
  return ((const float*)&v)[i];
}
__device__ __forceinline__ float4 f4fma(float s, float4 w, float4 a) {
  a.x = fmaf(s, w.x, a.x);
  a.y = fmaf(s, w.y, a.y);
  a.z = fmaf(s, w.z, a.z);
  a.w = fmaf(s, w.w, a.w);
  return a;
}
__device__ __forceinline__ float4 f4add(float4 a, float4 b) {
  a.x += b.x; a.y += b.y; a.z += b.z; a.w += b.w;
  return a;
}
__device__ __forceinline__ float lrelu(float x) { return x > 0.f ? x : 0.2f * x; }
__device__ __forceinline__ unsigned short f2bf(float f) {   // RNE
  unsigned int u = __float_as_uint(f);
  u = (u + 0x7fffu + ((u >> 16) & 1u)) >> 16;
  return (unsigned short)u;
}
__device__ __forceinline__ float bf2f(unsigned short h) {
  return __uint_as_float(((unsigned int)h) << 16);
}

#define F16(M) M(0) M(1) M(2) M(3) M(4) M(5) M(6) M(7) \
               M(8) M(9) M(10) M(11) M(12) M(13) M(14) M(15)

// ---------------------------------------------------------------------------
// init: cur = concat(user_emb, item_emb); cur16 = bf16(cur).
// ---------------------------------------------------------------------------
__global__ __launch_bounds__(256) void init_embed(
    const float* __restrict__ user_emb, const float* __restrict__ item_emb,
    float* __restrict__ cur, unsigned short* __restrict__ cur16, int with16)
{
  const size_t userF = (size_t)kNUsers * EMB;
  const size_t allF4 = (size_t)kNNodes * EMB / 4;
  const size_t i = (size_t)blockIdx.x * 256 + threadIdx.x;
  if (i >= allF4) return;
  const size_t f = i * 4;
  const float4 v = (f < userF) ? ((const float4*)user_emb)[i]
                               : ((const float4*)(item_emb))[(f - userF) / 4];
  ((float4*)cur)[i] = v;
  if (with16) {
    ushort4 h;
    h.x = f2bf(v.x); h.y = f2bf(v.y); h.z = f2bf(v.z); h.w = f2bf(v.w);
    ((ushort4*)cur16)[i] = h;
  }
}

// ---------------------------------------------------------------------------
// CSR build: range histogram -> range scan -> burst binning -> local place.
// ---------------------------------------------------------------------------

// Per-block LDS histogram over 586 ranges; one global atomic per (block,range).
__global__ __launch_bounds__(1024) void hist_ranges(
    const int* __restrict__ rows, int* __restrict__ rangeA)
{
  __shared__ int cnt[kNRanges];
  const int tid = threadIdx.x;
  const int e0  = blockIdx.x * kEdgesPerBin;
  int e1 = e0 + kEdgesPerBin;
  if (e1 > kNEdges) e1 = kNEdges;
  for (int b = tid; b < kNRanges; b += 1024) cnt[b] = 0;
  __syncthreads();
  for (int e = e0 + tid; e < e1; e += 1024)
    atomicAdd(&cnt[rows[e] >> kRngShift], 1);
  __syncthreads();
  for (int b = tid; b < kNRanges; b += 1024)
    if (cnt[b] > 0) atomicAdd(&rangeA[b], cnt[b]);
}

// Exclusive scan of the 586 range totals, in place (1 block).
__global__ __launch_bounds__(1024) void scan_ranges(
    int* __restrict__ rangeA, int* __restrict__ rowPtr)
{
  __shared__ int wsum[16];
  const int tid  = threadIdx.x;
  const int lane = tid & 63;
  const int wid  = tid >> 6;
  const int cnt  = (tid < kNRanges) ? rangeA[tid] : 0;
  int v = cnt;
#pragma unroll
  for (int off = 1; off < 64; off <<= 1) {
    const int n = __shfl_up(v, off, 64);
    if (lane >= off) v += n;
  }
  if (lane == 63) wsum[wid] = v;
  __syncthreads();
  if (tid == 0) {
    int s = 0;
#pragma unroll
    for (int w = 0; w < 16; ++w) { const int t = wsum[w]; wsum[w] = s; s += t; }
  }
  __syncthreads();
  if (tid < kNRanges) rangeA[tid] = wsum[wid] + v - cnt;
  if (tid == 0) {
    rangeA[kNRanges]  = kNEdges;
    rowPtr[kNNodes]   = kNEdges;
  }
}

// Bin edges into 586 row-ranges. Per block: LDS histogram, ONE global atomic
// per (block,range) reserving a contiguous burst off rangeStart, then scatter
// into the exclusively-owned burst. Record: col | localRow<<18.
__global__ __launch_bounds__(1024) void bin_edges(
    const int* __restrict__ rows, const int* __restrict__ cols,
    const float* __restrict__ vals, const int* __restrict__ rangeA,
    int* __restrict__ rangeCnt, int2* __restrict__ tmpE)
{
  __shared__ int cnt[kNRanges];
  __shared__ int base[kNRanges];
  const int tid = threadIdx.x;
  const int e0  = blockIdx.x * kEdgesPerBin;
  int e1 = e0 + kEdgesPerBin;
  if (e1 > kNEdges) e1 = kNEdges;

  for (int b = tid; b < kNRanges; b += 1024) cnt[b] = 0;
  __syncthreads();
  for (int e = e0 + tid; e < e1; e += 1024)
    atomicAdd(&cnt[rows[e] >> kRngShift], 1);
  __syncthreads();
  for (int b = tid; b < kNRanges; b += 1024) {
    const int c = cnt[b];
    base[b] = (c > 0) ? (rangeA[b] + atomicAdd(&rangeCnt[b], c)) : 0;
    cnt[b] = 0;
  }
  __syncthreads();
  for (int e = e0 + tid; e < e1; e += 1024) {
    const int r = rows[e];
    const int b = r >> kRngShift;
    const int rank = atomicAdd(&cnt[b], 1);
    tmpE[base[b] + rank] =
        make_int2(cols[e] | ((r & 255) << 18), __float_as_int(vals[e]));
  }
}

// One WG per range: derive local per-row CSR (LDS hist + block scan over the
// L2-resident slab), write rowPtr for its 256 rows, then place each edge at
// its exact CSR slot.
__global__ __launch_bounds__(256) void place_edges(
    const int2* __restrict__ tmpE, const int* __restrict__ rangeA,
    int2* __restrict__ edgeS, int* __restrict__ rowPtr)
{
  __shared__ int lcnt[256];
  __shared__ int lbase[256];
  __shared__ int ws[4];
  const int b    = blockIdx.x;
  const int r0   = b << kRngShift;
  const int tid  = threadIdx.x;
  const int lane = tid & 63;
  const int wid  = tid >> 6;
  const int start = rangeA[b];
  const int end   = rangeA[b + 1];

  lcnt[tid] = 0;
  __syncthreads();
  for (int e = start + tid; e < end; e += 256)
    atomicAdd(&lcnt[(tmpE[e].x >> 18) & 255], 1);
  __syncthreads();

  const int c = lcnt[tid];
  int v = c;
#pragma unroll
  for (int off = 1; off < 64; off <<= 1) {
    const int n = __shfl_up(v, off, 64);
    if (lane >= off) v += n;
  }
  if (lane == 63) ws[wid] = v;
  __syncthreads();
  int wadd = 0;
#pragma unroll
  for (int w = 0; w < 4; ++w) if (w < wid) wadd += ws[w];
  const int excl = v - c + wadd;
  lbase[tid] = start + excl;
  if (r0 + tid < kNNodes) rowPtr[r0 + tid] = start + excl;
  lcnt[tid] = 0;
  __syncthreads();

  for (int e = start + tid; e < end; e += 256) {
    const int2 cv = tmpE[e];
    const int rl  = (cv.x >> 18) & 255;
    const int rank = atomicAdd(&lcnt[rl], 1);
    edgeS[lbase[rl] + rank] = make_int2(cv.x & 0x3FFFF, cv.y);
  }
}

// ---------------------------------------------------------------------------
// CSR SpMM, bf16 gather, FUSED with t = n@W2 + b2.
// Epilogue: 4 independent FMA accumulators (dep chain 64 -> 16).
// ---------------------------------------------------------------------------
__global__ __launch_bounds__(256) void spmm_csr16f(
    const unsigned short* __restrict__ cur16, const int* __restrict__ rowPtr,
    const int2* __restrict__ edgeS, const float* __restrict__ W2,
    const float* __restrict__ b2, float* __restrict__ nbuf)
{
  const int lane = threadIdx.x & 63;
  const int r = (blockIdx.x << 2) | (threadIdx.x >> 6);
  if (r >= kNNodes) return;
  const int start = __builtin_amdgcn_readfirstlane(rowPtr[r]);
  const int end   = __builtin_amdgcn_readfirstlane(rowPtr[r + 1]);
  float a0 = 0.f, a1 = 0.f, a2 = 0.f, a3 = 0.f;
  int e = start;
  for (; e + 4 <= end; e += 4) {
    const int2 cv0 = edgeS[e];
    const int2 cv1 = edgeS[e + 1];
    const int2 cv2 = edgeS[e + 2];
    const int2 cv3 = edgeS[e + 3];
    const unsigned short u0 = cur16[(size_t)cv0.x * EMB + lane];
    const unsigned short u1 = cur16[(size_t)cv1.x * EMB + lane];
    const unsigned short u2 = cur16[(size_t)cv2.x * EMB + lane];
    const unsigned short u3 = cur16[(size_t)cv3.x * EMB + lane];
    a0 = fmaf(__int_as_float(cv0.y), bf2f(u0), a0);
    a1 = fmaf(__int_as_float(cv1.y), bf2f(u1), a1);
    a2 = fmaf(__int_as_float(cv2.y), bf2f(u2), a2);
    a3 = fmaf(__int_as_float(cv3.y), bf2f(u3), a3);
  }
  for (; e < end; ++e) {
    const int2 cv = edgeS[e];
    a0 = fmaf(__int_as_float(cv.y), bf2f(cur16[(size_t)cv.x * EMB + lane]), a0);
  }
  const float nsum = (a0 + a1) + (a2 + a3);

  // t[lane] = b2[lane] + sum_k n[k] * W2[k][lane]; 4 independent chains.
  float t0 = b2[lane], t1 = 0.f, t2 = 0.f, t3 = 0.f;
#pragma unroll
  for (int k = 0; k < 64; k += 4) {
    const float nk0 = __shfl(nsum, k,     64);   // compile-time -> v_readlane
    const float nk1 = __shfl(nsum, k + 1, 64);
    const float nk2 = __shfl(nsum, k + 2, 64);
    const float nk3 = __shfl(nsum, k + 3, 64);
    t0 = fmaf(nk0, W2[(k    ) * EMB + lane], t0);
    t1 = fmaf(nk1, W2[(k + 1) * EMB + lane], t1);
    t2 = fmaf(nk2, W2[(k + 2) * EMB + lane], t2);
    t3 = fmaf(nk3, W2[(k + 3) * EMB + lane], t3);
  }
  nbuf[(size_t)r * EMB + lane] = (t0 + t1) + (t2 + t3);
}

// fp32-gather variant (fallback when ws can't hold cur16) — unfused.
__global__ __launch_bounds__(256) void spmm_csr(
    const float* __restrict__ cur, const int* __restrict__ rowPtr,
    const int2* __restrict__ edgeS, float* __restrict__ nbuf)
{
  const int lane = threadIdx.x & 63;
  const int r = (blockIdx.x << 2) | (threadIdx.x >> 6);
  if (r >= kNNodes) return;
  const int start = __builtin_amdgcn_readfirstlane(rowPtr[r]);
  const int end   = __builtin_amdgcn_readfirstlane(rowPtr[r + 1]);
  float a0 = 0.f, a1 = 0.f, a2 = 0.f, a3 = 0.f;
  int e = start;
  for (; e + 4 <= end; e += 4) {
    const int2 cv0 = edgeS[e];
    const int2 cv1 = edgeS[e + 1];
    const int2 cv2 = edgeS[e + 2];
    const int2 cv3 = edgeS[e + 3];
    a0 = fmaf(__int_as_float(cv0.y), cur[(size_t)cv0.x * EMB + lane], a0);
    a1 = fmaf(__int_as_float(cv1.y), cur[(size_t)cv1.x * EMB + lane], a1);
    a2 = fmaf(__int_as_float(cv2.y), cur[(size_t)cv2.x * EMB + lane], a2);
    a3 = fmaf(__int_as_float(cv3.y), cur[(size_t)cv3.x * EMB + lane], a3);
  }
  for (; e < end; ++e) {
    const int2 cv = edgeS[e];
    a0 = fmaf(__int_as_float(cv.y), cur[(size_t)cv.x * EMB + lane], a0);
  }
  nbuf[(size_t)r * EMB + lane] = (a0 + a1) + (a2 + a3);
}

__global__ __launch_bounds__(256) void spmm_atomic(
    const float* __restrict__ cur, const int* __restrict__ rows,
    const int* __restrict__ cols, const float* __restrict__ vals,
    float* __restrict__ nbuf)
{
  const int lane = threadIdx.x & 63;
  int wv = (blockIdx.x << 2) | (threadIdx.x >> 6);
  wv = __builtin_amdgcn_readfirstlane(wv);
  int e0 = wv * kEPW;
  int e1 = e0 + kEPW;
  if (e1 > kNEdges) e1 = kNEdges;
  for (int e = e0; e < e1; ++e) {
    atomicAdd(nbuf + (size_t)rows[e] * EMB + lane,
              vals[e] * cur[(size_t)cols[e] * EMB + lane]);
  }
}

// ---------------------------------------------------------------------------
// Fallback-only: t = n@W2 + b2, in place over nbuf (for the non-CSR path).
// ---------------------------------------------------------------------------
__global__ __launch_bounds__(256) void transform_nbr(
    float* __restrict__ nbuf, const float* __restrict__ W2,
    const float* __restrict__ b2)
{
  const int node = blockIdx.x * 256 + threadIdx.x;
  if (node >= kNNodes) return;
  const float4* __restrict__ nr  = (const float4*)(nbuf + (size_t)node * EMB);
  const float4* __restrict__ b2v = (const float4*)b2;
#define DECL(j) float4 a##j = b2v[j];
  F16(DECL)
#undef DECL
#pragma unroll 4
  for (int k4 = 0; k4 < 16; ++k4) {
    const float4 nv = nr[k4];
#pragma unroll
    for (int kk = 0; kk < 4; ++kk) {
      const float ns = f4c(nv, kk);
      const float4* __restrict__ w2r = (const float4*)(W2 + (4 * k4 + kk) * EMB);
#define STEP(j) a##j = f4fma(ns, w2r[j], a##j);
      F16(STEP)
#undef STEP
    }
  }
  float4* __restrict__ outp = (float4*)(nbuf + (size_t)node * EMB);
#define STORE(j) outp[j] = a##j;
  F16(STORE)
#undef STORE
}

// ---------------------------------------------------------------------------
// Transform pass 2: cur = lrelu(x@W1 + b1 + b2 + (t*x)@W2 + t), t from nbuf.
// Fused bf16 shadow: also emits cur16 when with16 (refresh16 eliminated).
// ---------------------------------------------------------------------------
__global__ __launch_bounds__(256) void transform_self(
    float* __restrict__ cur, const float* __restrict__ nbuf,
    const float* __restrict__ W1, const float* __restrict__ b1,
    const float* __restrict__ b2, const float* __restrict__ W2,
    unsigned short* __restrict__ cur16, int with16)
{
  const int node = blockIdx.x * 256 + threadIdx.x;
  if (node >= kNNodes) return;
  const float4* __restrict__ xr  = (const float4*)(cur  + (size_t)node * EMB);
  const float4* __restrict__ tr  = (const float4*)(nbuf + (size_t)node * EMB);
  const float4* __restrict__ b1v = (const float4*)b1;
  const float4* __restrict__ b2v = (const float4*)b2;
#define DECL(j) float4 a##j = f4add(b1v[j], b2v[j]);
  F16(DECL)
#undef DECL
#pragma unroll 2
  for (int k4 = 0; k4 < 16; ++k4) {
    const float4 xv = xr[k4];
    const float4 tv = tr[k4];
#pragma unroll
    for (int kk = 0; kk < 4; ++kk) {
      const float xs = f4c(xv, kk);
      const float ms = f4c(tv, kk) * xs;
      const int k = 4 * k4 + kk;
      const float4* __restrict__ w1r = (const float4*)(W1 + k * EMB);
      const float4* __restrict__ w2r = (const float4*)(W2 + k * EMB);
#define STEP(j) a##j = f4fma(xs, w1r[j], a##j); a##j = f4fma(ms, w2r[j], a##j);
      F16(STEP)
#undef STEP
    }
  }
  float4* __restrict__ outp = (float4*)(cur + (size_t)node * EMB);
  ushort4* __restrict__ o16 = (ushort4*)(cur16 + (size_t)node * EMB);
#define STORE(j) { const float4 tj = tr[j]; float4 r;          \
    r.x = lrelu(a##j.x + tj.x); r.y = lrelu(a##j.y + tj.y);    \
    r.z = lrelu(a##j.z + tj.z); r.w = lrelu(a##j.w + tj.w);    \
    outp[j] = r;                                               \
    if (with16) { ushort4 h;                                   \
      h.x = f2bf(r.x); h.y = f2bf(r.y);                        \
      h.z = f2bf(r.z); h.w = f2bf(r.w);                        \
      o16[j] = h; } }
  F16(STORE)
#undef STORE
}

// ---------------------------------------------------------------------------
__global__ __launch_bounds__(256) void gather_out(
    const float* __restrict__ cur, const int* __restrict__ users,
    const int* __restrict__ pos, const int* __restrict__ neg,
    float* __restrict__ out, int layer)
{
  const int t    = blockIdx.x * 256 + threadIdx.x;
  const int lane = t & 63;
  const int rid  = t >> 6;
  if (rid >= 3 * kBatch) return;
  const int seg = rid / kBatch;
  const int b   = rid - seg * kBatch;
  int idx;
  if (seg == 0)      idx = users[b];
  else if (seg == 1) idx = pos[b] + kNUsers;
  else               idx = neg[b] + kNUsers;
  out[(size_t)rid * 256 + layer * EMB + lane] = cur[(size_t)idx * EMB + lane];
}

// ---------------------------------------------------------------------------
extern "C" void kernel_launch(void* const* d_in, const int* in_sizes, int n_in,
                              void* d_out, int out_size, void* d_ws, size_t ws_size,
                              hipStream_t stream) {
  const int*   users    = (const int*)d_in[0];
  const int*   pos      = (const int*)d_in[1];
  const int*   neg      = (const int*)d_in[2];
  const int*   rows     = (const int*)d_in[3];
  const int*   cols     = (const int*)d_in[4];
  const float* vals     = (const float*)d_in[5];
  const float* user_emb = (const float*)d_in[6];
  const float* item_emb = (const float*)d_in[7];
  const float* W1s      = (const float*)d_in[8];
  const float* b1s      = (const float*)d_in[9];
  const float* W2s      = (const float*)d_in[10];
  const float* b2s      = (const float*)d_in[11];
  float* out = (float*)d_out;

  const size_t nodeF = (size_t)kNNodes * EMB;
  float* cur  = (float*)d_ws;                               // 38.4 MB
  float* nbuf = cur + nodeF;                                // 38.4 MB (tmpE alias)
  int2*  edgeS     = (int2*)(nbuf + nodeF);                 // 38.4 MB
  int*   rowPtr    = (int*)(edgeS + kNEdges);               // 600 KB (+1)
  int*   rangeA    = rowPtr + (kNNodes + 1);                // 2.3 KB (+1)
  int*   rangeCnt  = rangeA + (kNRanges + 1);               // 2.3 KB
  unsigned short* cur16 = (unsigned short*)(rangeCnt + kNRanges);  // 19.2 MB
  int2*  tmpE = (int2*)nbuf;                                // binned records
  const size_t neededCsr = (size_t)((char*)cur16 - (char*)d_ws);
  const size_t needed16  = neededCsr + nodeF * sizeof(unsigned short);
  const bool useCsr = ws_size >= neededCsr;
  const bool use16  = useCsr && ws_size >= needed16;

  const dim3 blk(256);
  const int iblocks = (int)((nodeF / 4 + 255) / 256);       // 9375
  const int gblocks = (3 * kBatch * EMB + 255) / 256;       // 12288
  const int rblocks = (kNNodes + 3) / 4;                    // 37500
  const int tblocks = (kNNodes + 255) / 256;                // 586

  init_embed<<<iblocks, blk, 0, stream>>>(user_emb, item_emb, cur, cur16,
                                          use16 ? 1 : 0);

  if (useCsr) {
    // zero rangeA (totals) + rangeCnt (burst frontiers) — contiguous
    hipMemsetAsync(rangeA, 0, (size_t)(2 * kNRanges + 1) * sizeof(int), stream);
    hist_ranges<<<kBinBlocks, dim3(1024), 0, stream>>>(rows, rangeA);
    scan_ranges<<<1, 1024, 0, stream>>>(rangeA, rowPtr);
    bin_edges<<<kBinBlocks, dim3(1024), 0, stream>>>(rows, cols, vals, rangeA,
                                                     rangeCnt, tmpE);
    place_edges<<<kNRanges, blk, 0, stream>>>(tmpE, rangeA, edgeS, rowPtr);
  }

  gather_out<<<gblocks, blk, 0, stream>>>(cur, users, pos, neg, out, 0);

  for (int L = 0; L < kLayers; ++L) {
    const float* W1 = W1s + L * EMB * EMB;
    const float* b1 = b1s + L * EMB;
    const float* W2 = W2s + L * EMB * EMB;
    const float* b2 = b2s + L * EMB;
    if (useCsr && use16) {
      // fused: nbuf <- t = (A @ cur) @ W2 + b2
      spmm_csr16f<<<rblocks, blk, 0, stream>>>(cur16, rowPtr, edgeS, W2, b2,
                                               nbuf);
    } else if (useCsr) {
      spmm_csr<<<rblocks, blk, 0, stream>>>(cur, rowPtr, edgeS, nbuf);
      transform_nbr<<<tblocks, blk, 0, stream>>>(nbuf, W2, b2);
    } else {
      hipMemsetAsync(nbuf, 0, nodeF * sizeof(float), stream);
      const int sblocks = (((kNEdges + kEPW - 1) / kEPW) + 3) / 4;
      spmm_atomic<<<sblocks, blk, 0, stream>>>(cur, rows, cols, vals, nbuf);
      transform_nbr<<<tblocks, blk, 0, stream>>>(nbuf, W2, b2);
    }
    const int w16 = (use16 && L + 1 < kLayers) ? 1 : 0;
    transform_self<<<tblocks, blk, 0, stream>>>(cur, nbuf, W1, b1, b2, W2,
                                                cur16, w16);
    gather_out<<<gblocks, blk, 0, stream>>>(cur, users, pos, neg, out, L + 1);
  }
}

// Round 11
// 1163.428 us; speedup vs baseline: 1.0994x; 1.0994x over previous
//
#include <hip/hip_runtime.h>

// NGCF forward on gfx950 — round 17: revert R16's transform_self bf16 fusion
// (pressure cliff, +45us/layer — R9 failure class) back to exact R15 config;
// keep the (null but harmless) 4-acc spmm epilogue. One new change:
// bin_edges LDS-staged sort. R16 counters: bin_edges WRITE=109MB vs 38.4
// ideal (2.8x) — 8B scatter writes dribble into burst lines across the whole
// scan, lines evicted partially assembled. Fix: per-4096-edge sub-batch
// {LDS hist+rank, 586-scan, global burst reserve, scatter into 32KB LDS
// buffer, contiguous ordered copy-out} -> lines fully assembled, amp ~1.

#define EMB 64

constexpr int kNUsers = 100000;
constexpr int kNItems = 50000;
constexpr int kNNodes = 150000;
constexpr int kNEdges = 4800000;
constexpr int kBatch  = 16384;
constexpr int kLayers = 3;
constexpr int kRngShift = 8;                     // 256 rows per range
constexpr int kNRanges  = (kNNodes + 255) >> 8;  // 586
constexpr int kEdgesPerBin = 16384;              // edges per bin block
constexpr int kBinBlocks = (kNEdges + kEdgesPerBin - 1) / kEdgesPerBin; // 293
constexpr int kSub    = 4096;                    // LDS-staged sub-batch
constexpr int kEPW    = 16;                      // fallback only

__device__ __forceinline__ float f4c(const float4& v, int i) {
  return ((const float*)&v)[i];
}
__device__ __forceinline__ float4 f4fma(float s, float4 w, float4 a) {
  a.x = fmaf(s, w.x, a.x);
  a.y = fmaf(s, w.y, a.y);
  a.z = fmaf(s, w.z, a.z);
  a.w = fmaf(s, w.w, a.w);
  return a;
}
__device__ __forceinline__ float4 f4add(float4 a, float4 b) {
  a.x += b.x; a.y += b.y; a.z += b.z; a.w += b.w;
  return a;
}
__device__ __forceinline__ float lrelu(float x) { return x > 0.f ? x : 0.2f * x; }
__device__ __forceinline__ unsigned short f2bf(float f) {   // RNE
  unsigned int u = __float_as_uint(f);
  u = (u + 0x7fffu + ((u >> 16) & 1u)) >> 16;
  return (unsigned short)u;
}
__device__ __forceinline__ float bf2f(unsigned short h) {
  return __uint_as_float(((unsigned int)h) << 16);
}

#define F16(M) M(0) M(1) M(2) M(3) M(4) M(5) M(6) M(7) \
               M(8) M(9) M(10) M(11) M(12) M(13) M(14) M(15)

// ---------------------------------------------------------------------------
// init: cur = concat(user_emb, item_emb); cur16 = bf16(cur).
// ---------------------------------------------------------------------------
__global__ __launch_bounds__(256) void init_embed(
    const float* __restrict__ user_emb, const float* __restrict__ item_emb,
    float* __restrict__ cur, unsigned short* __restrict__ cur16, int with16)
{
  const size_t userF = (size_t)kNUsers * EMB;
  const size_t allF4 = (size_t)kNNodes * EMB / 4;
  const size_t i = (size_t)blockIdx.x * 256 + threadIdx.x;
  if (i >= allF4) return;
  const size_t f = i * 4;
  const float4 v = (f < userF) ? ((const float4*)user_emb)[i]
                               : ((const float4*)(item_emb))[(f - userF) / 4];
  ((float4*)cur)[i] = v;
  if (with16) {
    ushort4 h;
    h.x = f2bf(v.x); h.y = f2bf(v.y); h.z = f2bf(v.z); h.w = f2bf(v.w);
    ((ushort4*)cur16)[i] = h;
  }
}

// Streaming bf16 shadow refresh: cur16 = bf16(cur).
__global__ __launch_bounds__(256) void refresh16(
    const float* __restrict__ cur, unsigned short* __restrict__ cur16)
{
  const size_t allF4 = (size_t)kNNodes * EMB / 4;
  const size_t i = (size_t)blockIdx.x * 256 + threadIdx.x;
  if (i >= allF4) return;
  const float4 v = ((const float4*)cur)[i];
  ushort4 h;
  h.x = f2bf(v.x); h.y = f2bf(v.y); h.z = f2bf(v.z); h.w = f2bf(v.w);
  ((ushort4*)cur16)[i] = h;
}

// ---------------------------------------------------------------------------
// CSR build: range histogram -> range scan -> burst binning -> local place.
// ---------------------------------------------------------------------------

// Per-block LDS histogram over 586 ranges; one global atomic per (block,range).
__global__ __launch_bounds__(1024) void hist_ranges(
    const int* __restrict__ rows, int* __restrict__ rangeA)
{
  __shared__ int cnt[kNRanges];
  const int tid = threadIdx.x;
  const int e0  = blockIdx.x * kEdgesPerBin;
  int e1 = e0 + kEdgesPerBin;
  if (e1 > kNEdges) e1 = kNEdges;
  for (int b = tid; b < kNRanges; b += 1024) cnt[b] = 0;
  __syncthreads();
  for (int e = e0 + tid; e < e1; e += 1024)
    atomicAdd(&cnt[rows[e] >> kRngShift], 1);
  __syncthreads();
  for (int b = tid; b < kNRanges; b += 1024)
    if (cnt[b] > 0) atomicAdd(&rangeA[b], cnt[b]);
}

// Exclusive scan of the 586 range totals, in place (1 block).
__global__ __launch_bounds__(1024) void scan_ranges(
    int* __restrict__ rangeA, int* __restrict__ rowPtr)
{
  __shared__ int wsum[16];
  const int tid  = threadIdx.x;
  const int lane = tid & 63;
  const int wid  = tid >> 6;
  const int cnt  = (tid < kNRanges) ? rangeA[tid] : 0;
  int v = cnt;
#pragma unroll
  for (int off = 1; off < 64; off <<= 1) {
    const int n = __shfl_up(v, off, 64);
    if (lane >= off) v += n;
  }
  if (lane == 63) wsum[wid] = v;
  __syncthreads();
  if (tid == 0) {
    int s = 0;
#pragma unroll
    for (int w = 0; w < 16; ++w) { const int t = wsum[w]; wsum[w] = s; s += t; }
  }
  __syncthreads();
  if (tid < kNRanges) rangeA[tid] = wsum[wid] + v - cnt;
  if (tid == 0) {
    rangeA[kNRanges]  = kNEdges;
    rowPtr[kNNodes]   = kNEdges;
  }
}

// Bin edges into 586 row-ranges, LDS-staged: per 4096-edge sub-batch, build
// an LDS histogram (ranks from the same atomic), scan it, reserve global
// bursts, scatter records into a sorted LDS buffer, then copy out in order so
// every destination line is fully assembled in one streaming pass.
__global__ __launch_bounds__(1024) void bin_edges(
    const int* __restrict__ rows, const int* __restrict__ cols,
    const float* __restrict__ vals, const int* __restrict__ rangeA,
    int* __restrict__ rangeCnt, int2* __restrict__ tmpE)
{
  __shared__ int cnt[kNRanges];
  __shared__ int lofs[kNRanges];
  __shared__ int gbase[kNRanges];
  __shared__ int wsum[16];
  __shared__ int2 sbuf[kSub];
  __shared__ unsigned short grg[kSub];
  const int tid  = threadIdx.x;
  const int lane = tid & 63;
  const int wid  = tid >> 6;
  const int e0   = blockIdx.x * kEdgesPerBin;
  int e1 = e0 + kEdgesPerBin;
  if (e1 > kNEdges) e1 = kNEdges;

  for (int sb = e0; sb < e1; sb += kSub) {
    const int n = min(kSub, e1 - sb);
    for (int g = tid; g < kNRanges; g += 1024) cnt[g] = 0;
    __syncthreads();

    // load + histogram; rank comes from the same LDS atomic
    int  myg[4], myrank[4];
    int2 myrec[4];
#pragma unroll
    for (int k = 0; k < 4; ++k) {
      const int i = k * 1024 + tid;
      myg[k] = -1;
      if (i < n) {
        const int e = sb + i;
        const int r = rows[e];
        const int g = r >> kRngShift;
        myg[k]    = g;
        myrank[k] = atomicAdd(&cnt[g], 1);
        myrec[k]  = make_int2(cols[e] | ((r & 255) << 18),
                              __float_as_int(vals[e]));
      }
    }
    __syncthreads();

    // exclusive scan of cnt[0..585] -> lofs; reserve global bursts
    const int c = (tid < kNRanges) ? cnt[tid] : 0;
    int v = c;
#pragma unroll
    for (int off = 1; off < 64; off <<= 1) {
      const int x = __shfl_up(v, off, 64);
      if (lane >= off) v += x;
    }
    if (lane == 63) wsum[wid] = v;
    __syncthreads();
    if (tid == 0) {
      int s = 0;
#pragma unroll
      for (int w = 0; w < 16; ++w) { const int t = wsum[w]; wsum[w] = s; s += t; }
    }
    __syncthreads();
    if (tid < kNRanges) {
      const int excl = wsum[wid] + v - c;
      lofs[tid] = excl;
      gbase[tid] = (c > 0) ? (rangeA[tid] + atomicAdd(&rangeCnt[tid], c)) : 0;
    }
    __syncthreads();

    // scatter into sorted LDS buffer
#pragma unroll
    for (int k = 0; k < 4; ++k) {
      if (myg[k] >= 0) {
        const int slot = lofs[myg[k]] + myrank[k];
        sbuf[slot] = myrec[k];
        grg[slot]  = (unsigned short)myg[k];
      }
    }
    __syncthreads();

    // ordered copy-out: consecutive t -> consecutive dst within each burst
    for (int t = tid; t < n; t += 1024) {
      const int g = grg[t];
      tmpE[gbase[g] + (t - lofs[g])] = sbuf[t];
    }
    __syncthreads();
  }
}

// One WG per range: derive local per-row CSR (LDS hist + block scan over the
// L2-resident slab), write rowPtr for its 256 rows, then place each edge at
// its exact CSR slot.
__global__ __launch_bounds__(256) void place_edges(
    const int2* __restrict__ tmpE, const int* __restrict__ rangeA,
    int2* __restrict__ edgeS, int* __restrict__ rowPtr)
{
  __shared__ int lcnt[256];
  __shared__ int lbase[256];
  __shared__ int ws[4];
  const int b    = blockIdx.x;
  const int r0   = b << kRngShift;
  const int tid  = threadIdx.x;
  const int lane = tid & 63;
  const int wid  = tid >> 6;
  const int start = rangeA[b];
  const int end   = rangeA[b + 1];

  lcnt[tid] = 0;
  __syncthreads();
  for (int e = start + tid; e < end; e += 256)
    atomicAdd(&lcnt[(tmpE[e].x >> 18) & 255], 1);
  __syncthreads();

  const int c = lcnt[tid];
  int v = c;
#pragma unroll
  for (int off = 1; off < 64; off <<= 1) {
    const int n = __shfl_up(v, off, 64);
    if (lane >= off) v += n;
  }
  if (lane == 63) ws[wid] = v;
  __syncthreads();
  int wadd = 0;
#pragma unroll
  for (int w = 0; w < 4; ++w) if (w < wid) wadd += ws[w];
  const int excl = v - c + wadd;
  lbase[tid] = start + excl;
  if (r0 + tid < kNNodes) rowPtr[r0 + tid] = start + excl;
  lcnt[tid] = 0;
  __syncthreads();

  for (int e = start + tid; e < end; e += 256) {
    const int2 cv = tmpE[e];
    const int rl  = (cv.x >> 18) & 255;
    const int rank = atomicAdd(&lcnt[rl], 1);
    edgeS[lbase[rl] + rank] = make_int2(cv.x & 0x3FFFF, cv.y);
  }
}

// ---------------------------------------------------------------------------
// CSR SpMM, bf16 gather, FUSED with t = n@W2 + b2 (4 independent FMA chains).
// ---------------------------------------------------------------------------
__global__ __launch_bounds__(256) void spmm_csr16f(
    const unsigned short* __restrict__ cur16, const int* __restrict__ rowPtr,
    const int2* __restrict__ edgeS, const float* __restrict__ W2,
    const float* __restrict__ b2, float* __restrict__ nbuf)
{
  const int lane = threadIdx.x & 63;
  const int r = (blockIdx.x << 2) | (threadIdx.x >> 6);
  if (r >= kNNodes) return;
  const int start = __builtin_amdgcn_readfirstlane(rowPtr[r]);
  const int end   = __builtin_amdgcn_readfirstlane(rowPtr[r + 1]);
  float a0 = 0.f, a1 = 0.f, a2 = 0.f, a3 = 0.f;
  int e = start;
  for (; e + 4 <= end; e += 4) {
    const int2 cv0 = edgeS[e];
    const int2 cv1 = edgeS[e + 1];
    const int2 cv2 = edgeS[e + 2];
    const int2 cv3 = edgeS[e + 3];
    const unsigned short u0 = cur16[(size_t)cv0.x * EMB + lane];
    const unsigned short u1 = cur16[(size_t)cv1.x * EMB + lane];
    const unsigned short u2 = cur16[(size_t)cv2.x * EMB + lane];
    const unsigned short u3 = cur16[(size_t)cv3.x * EMB + lane];
    a0 = fmaf(__int_as_float(cv0.y), bf2f(u0), a0);
    a1 = fmaf(__int_as_float(cv1.y), bf2f(u1), a1);
    a2 = fmaf(__int_as_float(cv2.y), bf2f(u2), a2);
    a3 = fmaf(__int_as_float(cv3.y), bf2f(u3), a3);
  }
  for (; e < end; ++e) {
    const int2 cv = edgeS[e];
    a0 = fmaf(__int_as_float(cv.y), bf2f(cur16[(size_t)cv.x * EMB + lane]), a0);
  }
  const float nsum = (a0 + a1) + (a2 + a3);

  float t0 = b2[lane], t1 = 0.f, t2 = 0.f, t3 = 0.f;
#pragma unroll
  for (int k = 0; k < 64; k += 4) {
    const float nk0 = __shfl(nsum, k,     64);   // compile-time -> v_readlane
    const float nk1 = __shfl(nsum, k + 1, 64);
    const float nk2 = __shfl(nsum, k + 2, 64);
    const float nk3 = __shfl(nsum, k + 3, 64);
    t0 = fmaf(nk0, W2[(k    ) * EMB + lane], t0);
    t1 = fmaf(nk1, W2[(k + 1) * EMB + lane], t1);
    t2 = fmaf(nk2, W2[(k + 2) * EMB + lane], t2);
    t3 = fmaf(nk3, W2[(k + 3) * EMB + lane], t3);
  }
  nbuf[(size_t)r * EMB + lane] = (t0 + t1) + (t2 + t3);
}

// fp32-gather variant (fallback when ws can't hold cur16) — unfused.
__global__ __launch_bounds__(256) void spmm_csr(
    const float* __restrict__ cur, const int* __restrict__ rowPtr,
    const int2* __restrict__ edgeS, float* __restrict__ nbuf)
{
  const int lane = threadIdx.x & 63;
  const int r = (blockIdx.x << 2) | (threadIdx.x >> 6);
  if (r >= kNNodes) return;
  const int start = __builtin_amdgcn_readfirstlane(rowPtr[r]);
  const int end   = __builtin_amdgcn_readfirstlane(rowPtr[r + 1]);
  float a0 = 0.f, a1 = 0.f, a2 = 0.f, a3 = 0.f;
  int e = start;
  for (; e + 4 <= end; e += 4) {
    const int2 cv0 = edgeS[e];
    const int2 cv1 = edgeS[e + 1];
    const int2 cv2 = edgeS[e + 2];
    const int2 cv3 = edgeS[e + 3];
    a0 = fmaf(__int_as_float(cv0.y), cur[(size_t)cv0.x * EMB + lane], a0);
    a1 = fmaf(__int_as_float(cv1.y), cur[(size_t)cv1.x * EMB + lane], a1);
    a2 = fmaf(__int_as_float(cv2.y), cur[(size_t)cv2.x * EMB + lane], a2);
    a3 = fmaf(__int_as_float(cv3.y), cur[(size_t)cv3.x * EMB + lane], a3);
  }
  for (; e < end; ++e) {
    const int2 cv = edgeS[e];
    a0 = fmaf(__int_as_float(cv.y), cur[(size_t)cv.x * EMB + lane], a0);
  }
  nbuf[(size_t)r * EMB + lane] = (a0 + a1) + (a2 + a3);
}

__global__ __launch_bounds__(256) void spmm_atomic(
    const float* __restrict__ cur, const int* __restrict__ rows,
    const int* __restrict__ cols, const float* __restrict__ vals,
    float* __restrict__ nbuf)
{
  const int lane = threadIdx.x & 63;
  int wv = (blockIdx.x << 2) | (threadIdx.x >> 6);
  wv = __builtin_amdgcn_readfirstlane(wv);
  int e0 = wv * kEPW;
  int e1 = e0 + kEPW;
  if (e1 > kNEdges) e1 = kNEdges;
  for (int e = e0; e < e1; ++e) {
    atomicAdd(nbuf + (size_t)rows[e] * EMB + lane,
              vals[e] * cur[(size_t)cols[e] * EMB + lane]);
  }
}

// ---------------------------------------------------------------------------
// Fallback-only: t = n@W2 + b2, in place over nbuf (for the non-CSR path).
// ---------------------------------------------------------------------------
__global__ __launch_bounds__(256) void transform_nbr(
    float* __restrict__ nbuf, const float* __restrict__ W2,
    const float* __restrict__ b2)
{
  const int node = blockIdx.x * 256 + threadIdx.x;
  if (node >= kNNodes) return;
  const float4* __restrict__ nr  = (const float4*)(nbuf + (size_t)node * EMB);
  const float4* __restrict__ b2v = (const float4*)b2;
#define DECL(j) float4 a##j = b2v[j];
  F16(DECL)
#undef DECL
#pragma unroll 4
  for (int k4 = 0; k4 < 16; ++k4) {
    const float4 nv = nr[k4];
#pragma unroll
    for (int kk = 0; kk < 4; ++kk) {
      const float ns = f4c(nv, kk);
      const float4* __restrict__ w2r = (const float4*)(W2 + (4 * k4 + kk) * EMB);
#define STEP(j) a##j = f4fma(ns, w2r[j], a##j);
      F16(STEP)
#undef STEP
    }
  }
  float4* __restrict__ outp = (float4*)(nbuf + (size_t)node * EMB);
#define STORE(j) outp[j] = a##j;
  F16(STORE)
#undef STORE
}

// ---------------------------------------------------------------------------
// Transform pass 2: cur = lrelu(x@W1 + b1 + b2 + (t*x)@W2 + t), t from nbuf.
// (R15 form — the bf16-fused variant regressed, R16 post-mortem.)
// ---------------------------------------------------------------------------
__global__ __launch_bounds__(256) void transform_self(
    float* __restrict__ cur, const float* __restrict__ nbuf,
    const float* __restrict__ W1, const float* __restrict__ b1,
    const float* __restrict__ b2, const float* __restrict__ W2)
{
  const int node = blockIdx.x * 256 + threadIdx.x;
  if (node >= kNNodes) return;
  const float4* __restrict__ xr  = (const float4*)(cur  + (size_t)node * EMB);
  const float4* __restrict__ tr  = (const float4*)(nbuf + (size_t)node * EMB);
  const float4* __restrict__ b1v = (const float4*)b1;
  const float4* __restrict__ b2v = (const float4*)b2;
#define DECL(j) float4 a##j = f4add(b1v[j], b2v[j]);
  F16(DECL)
#undef DECL
#pragma unroll 2
  for (int k4 = 0; k4 < 16; ++k4) {
    const float4 xv = xr[k4];
    const float4 tv = tr[k4];
#pragma unroll
    for (int kk = 0; kk < 4; ++kk) {
      const float xs = f4c(xv, kk);
      const float ms = f4c(tv, kk) * xs;
      const int k = 4 * k4 + kk;
      const float4* __restrict__ w1r = (const float4*)(W1 + k * EMB);
      const float4* __restrict__ w2r = (const float4*)(W2 + k * EMB);
#define STEP(j) a##j = f4fma(xs, w1r[j], a##j); a##j = f4fma(ms, w2r[j], a##j);
      F16(STEP)
#undef STEP
    }
  }
  float4* __restrict__ outp = (float4*)(cur + (size_t)node * EMB);
#define STORE(j) { const float4 tj = tr[j]; float4 r;          \
    r.x = lrelu(a##j.x + tj.x); r.y = lrelu(a##j.y + tj.y);    \
    r.z = lrelu(a##j.z + tj.z); r.w = lrelu(a##j.w + tj.w);    \
    outp[j] = r; }
  F16(STORE)
#undef STORE
}

// ---------------------------------------------------------------------------
__global__ __launch_bounds__(256) void gather_out(
    const float* __restrict__ cur, const int* __restrict__ users,
    const int* __restrict__ pos, const int* __restrict__ neg,
    float* __restrict__ out, int layer)
{
  const int t    = blockIdx.x * 256 + threadIdx.x;
  const int lane = t & 63;
  const int rid  = t >> 6;
  if (rid >= 3 * kBatch) return;
  const int seg = rid / kBatch;
  const int b   = rid - seg * kBatch;
  int idx;
  if (seg == 0)      idx = users[b];
  else if (seg == 1) idx = pos[b] + kNUsers;
  else               idx = neg[b] + kNUsers;
  out[(size_t)rid * 256 + layer * EMB + lane] = cur[(size_t)idx * EMB + lane];
}

// ---------------------------------------------------------------------------
extern "C" void kernel_launch(void* const* d_in, const int* in_sizes, int n_in,
                              void* d_out, int out_size, void* d_ws, size_t ws_size,
                              hipStream_t stream) {
  const int*   users    = (const int*)d_in[0];
  const int*   pos      = (const int*)d_in[1];
  const int*   neg      = (const int*)d_in[2];
  const int*   rows     = (const int*)d_in[3];
  const int*   cols     = (const int*)d_in[4];
  const float* vals     = (const float*)d_in[5];
  const float* user_emb = (const float*)d_in[6];
  const float* item_emb = (const float*)d_in[7];
  const float* W1s      = (const float*)d_in[8];
  const float* b1s      = (const float*)d_in[9];
  const float* W2s      = (const float*)d_in[10];
  const float* b2s      = (const float*)d_in[11];
  float* out = (float*)d_out;

  const size_t nodeF = (size_t)kNNodes * EMB;
  float* cur  = (float*)d_ws;                               // 38.4 MB
  float* nbuf = cur + nodeF;                                // 38.4 MB (tmpE alias)
  int2*  edgeS     = (int2*)(nbuf + nodeF);                 // 38.4 MB
  int*   rowPtr    = (int*)(edgeS + kNEdges);               // 600 KB (+1)
  int*   rangeA    = rowPtr + (kNNodes + 1);                // 2.3 KB (+1)
  int*   rangeCnt  = rangeA + (kNRanges + 1);               // 2.3 KB
  unsigned short* cur16 = (unsigned short*)(rangeCnt + kNRanges);  // 19.2 MB
  int2*  tmpE = (int2*)nbuf;                                // binned records
  const size_t neededCsr = (size_t)((char*)cur16 - (char*)d_ws);
  const size_t needed16  = neededCsr + nodeF * sizeof(unsigned short);
  const bool useCsr = ws_size >= neededCsr;
  const bool use16  = useCsr && ws_size >= needed16;

  const dim3 blk(256);
  const int iblocks = (int)((nodeF / 4 + 255) / 256);       // 9375
  const int gblocks = (3 * kBatch * EMB + 255) / 256;       // 12288
  const int rblocks = (kNNodes + 3) / 4;                    // 37500
  const int tblocks = (kNNodes + 255) / 256;                // 586

  init_embed<<<iblocks, blk, 0, stream>>>(user_emb, item_emb, cur, cur16,
                                          use16 ? 1 : 0);

  if (useCsr) {
    // zero rangeA (totals) + rangeCnt (burst frontiers) — contiguous
    hipMemsetAsync(rangeA, 0, (size_t)(2 * kNRanges + 1) * sizeof(int), stream);
    hist_ranges<<<kBinBlocks, dim3(1024), 0, stream>>>(rows, rangeA);
    scan_ranges<<<1, 1024, 0, stream>>>(rangeA, rowPtr);
    bin_edges<<<kBinBlocks, dim3(1024), 0, stream>>>(rows, cols, vals, rangeA,
                                                     rangeCnt, tmpE);
    place_edges<<<kNRanges, blk, 0, stream>>>(tmpE, rangeA, edgeS, rowPtr);
  }

  gather_out<<<gblocks, blk, 0, stream>>>(cur, users, pos, neg, out, 0);

  for (int L = 0; L < kLayers; ++L) {
    const float* W1 = W1s + L * EMB * EMB;
    const float* b1 = b1s + L * EMB;
    const float* W2 = W2s + L * EMB * EMB;
    const float* b2 = b2s + L * EMB;
    if (useCsr && use16) {
      // fused: nbuf <- t = (A @ cur) @ W2 + b2
      spmm_csr16f<<<rblocks, blk, 0, stream>>>(cur16, rowPtr, edgeS, W2, b2,
                                               nbuf);
    } else if (useCsr) {
      spmm_csr<<<rblocks, blk, 0, stream>>>(cur, rowPtr, edgeS, nbuf);
      transform_nbr<<<tblocks, blk, 0, stream>>>(nbuf, W2, b2);
    } else {
      hipMemsetAsync(nbuf, 0, nodeF * sizeof(float), stream);
      const int sblocks = (((kNEdges + kEPW - 1) / kEPW) + 3) / 4;
      spmm_atomic<<<sblocks, blk, 0, stream>>>(cur, rows, cols, vals, nbuf);
      transform_nbr<<<tblocks, blk, 0, stream>>>(nbuf, W2, b2);
    }
    transform_self<<<tblocks, blk, 0, stream>>>(cur, nbuf, W1, b1, b2, W2);
    if (use16 && L + 1 < kLayers)
      refresh16<<<iblocks, blk, 0, stream>>>(cur, cur16);
    gather_out<<<gblocks, blk, 0, stream>>>(cur, users, pos, neg, out, L + 1);
  }
}

// Round 12
// 1127.676 us; speedup vs baseline: 1.1342x; 1.0317x over previous
//
#include <hip/hip_runtime.h>

// NGCF forward on gfx950 — round 18: deepen spmm gather MLP 4 -> 8.
// R17 insight: cur16 (19.2 MB) is L3-resident, so spmm's 525 MB FETCH is
// L2-miss traffic served by Infinity Cache — the ~4 TB/s plateau may be an
// MLP limit (both prior "ceiling" kernels used the same 4-deep unroll, and
// in-order vmcnt + edgeS->gather dependency caps outstanding loads), not a
// hardware wall. Single change vs R17: edge loop unrolled 8-wide with 8
// independent accumulators (8 gathers in flight). VGPR 32 -> ~40, no
// occupancy change. Null => fabric ceiling, spmm closed.

#define EMB 64

constexpr int kNUsers = 100000;
constexpr int kNItems = 50000;
constexpr int kNNodes = 150000;
constexpr int kNEdges = 4800000;
constexpr int kBatch  = 16384;
constexpr int kLayers = 3;
constexpr int kRngShift = 8;                     // 256 rows per range
constexpr int kNRanges  = (kNNodes + 255) >> 8;  // 586
constexpr int kEdgesPerBin = 16384;              // edges per bin block
constexpr int kBinBlocks = (kNEdges + kEdgesPerBin - 1) / kEdgesPerBin; // 293
constexpr int kSub    = 4096;                    // LDS-staged sub-batch
constexpr int kEPW    = 16;                      // fallback only

__device__ __forceinline__ float f4c(const float4& v, int i) {
  return ((const float*)&v)[i];
}
__device__ __forceinline__ float4 f4fma(float s, float4 w, float4 a) {
  a.x = fmaf(s, w.x, a.x);
  a.y = fmaf(s, w.y, a.y);
  a.z = fmaf(s, w.z, a.z);
  a.w = fmaf(s, w.w, a.w);
  return a;
}
__device__ __forceinline__ float4 f4add(float4 a, float4 b) {
  a.x += b.x; a.y += b.y; a.z += b.z; a.w += b.w;
  return a;
}
__device__ __forceinline__ float lrelu(float x) { return x > 0.f ? x : 0.2f * x; }
__device__ __forceinline__ unsigned short f2bf(float f) {   // RNE
  unsigned int u = __float_as_uint(f);
  u = (u + 0x7fffu + ((u >> 16) & 1u)) >> 16;
  return (unsigned short)u;
}
__device__ __forceinline__ float bf2f(unsigned short h) {
  return __uint_as_float(((unsigned int)h) << 16);
}

#define F16(M) M(0) M(1) M(2) M(3) M(4) M(5) M(6) M(7) \
               M(8) M(9) M(10) M(11) M(12) M(13) M(14) M(15)

// ---------------------------------------------------------------------------
// init: cur = concat(user_emb, item_emb); cur16 = bf16(cur).
// ---------------------------------------------------------------------------
__global__ __launch_bounds__(256) void init_embed(
    const float* __restrict__ user_emb, const float* __restrict__ item_emb,
    float* __restrict__ cur, unsigned short* __restrict__ cur16, int with16)
{
  const size_t userF = (size_t)kNUsers * EMB;
  const size_t allF4 = (size_t)kNNodes * EMB / 4;
  const size_t i = (size_t)blockIdx.x * 256 + threadIdx.x;
  if (i >= allF4) return;
  const size_t f = i * 4;
  const float4 v = (f < userF) ? ((const float4*)user_emb)[i]
                               : ((const float4*)(item_emb))[(f - userF) / 4];
  ((float4*)cur)[i] = v;
  if (with16) {
    ushort4 h;
    h.x = f2bf(v.x); h.y = f2bf(v.y); h.z = f2bf(v.z); h.w = f2bf(v.w);
    ((ushort4*)cur16)[i] = h;
  }
}

// Streaming bf16 shadow refresh: cur16 = bf16(cur).
__global__ __launch_bounds__(256) void refresh16(
    const float* __restrict__ cur, unsigned short* __restrict__ cur16)
{
  const size_t allF4 = (size_t)kNNodes * EMB / 4;
  const size_t i = (size_t)blockIdx.x * 256 + threadIdx.x;
  if (i >= allF4) return;
  const float4 v = ((const float4*)cur)[i];
  ushort4 h;
  h.x = f2bf(v.x); h.y = f2bf(v.y); h.z = f2bf(v.z); h.w = f2bf(v.w);
  ((ushort4*)cur16)[i] = h;
}

// ---------------------------------------------------------------------------
// CSR build: range histogram -> range scan -> burst binning -> local place.
// ---------------------------------------------------------------------------

// Per-block LDS histogram over 586 ranges; one global atomic per (block,range).
__global__ __launch_bounds__(1024) void hist_ranges(
    const int* __restrict__ rows, int* __restrict__ rangeA)
{
  __shared__ int cnt[kNRanges];
  const int tid = threadIdx.x;
  const int e0  = blockIdx.x * kEdgesPerBin;
  int e1 = e0 + kEdgesPerBin;
  if (e1 > kNEdges) e1 = kNEdges;
  for (int b = tid; b < kNRanges; b += 1024) cnt[b] = 0;
  __syncthreads();
  for (int e = e0 + tid; e < e1; e += 1024)
    atomicAdd(&cnt[rows[e] >> kRngShift], 1);
  __syncthreads();
  for (int b = tid; b < kNRanges; b += 1024)
    if (cnt[b] > 0) atomicAdd(&rangeA[b], cnt[b]);
}

// Exclusive scan of the 586 range totals, in place (1 block).
__global__ __launch_bounds__(1024) void scan_ranges(
    int* __restrict__ rangeA, int* __restrict__ rowPtr)
{
  __shared__ int wsum[16];
  const int tid  = threadIdx.x;
  const int lane = tid & 63;
  const int wid  = tid >> 6;
  const int cnt  = (tid < kNRanges) ? rangeA[tid] : 0;
  int v = cnt;
#pragma unroll
  for (int off = 1; off < 64; off <<= 1) {
    const int n = __shfl_up(v, off, 64);
    if (lane >= off) v += n;
  }
  if (lane == 63) wsum[wid] = v;
  __syncthreads();
  if (tid == 0) {
    int s = 0;
#pragma unroll
    for (int w = 0; w < 16; ++w) { const int t = wsum[w]; wsum[w] = s; s += t; }
  }
  __syncthreads();
  if (tid < kNRanges) rangeA[tid] = wsum[wid] + v - cnt;
  if (tid == 0) {
    rangeA[kNRanges]  = kNEdges;
    rowPtr[kNNodes]   = kNEdges;
  }
}

// Bin edges into 586 row-ranges, LDS-staged: per 4096-edge sub-batch, build
// an LDS histogram (ranks from the same atomic), scan it, reserve global
// bursts, scatter records into a sorted LDS buffer, then copy out in order so
// every destination line is fully assembled in one streaming pass.
__global__ __launch_bounds__(1024) void bin_edges(
    const int* __restrict__ rows, const int* __restrict__ cols,
    const float* __restrict__ vals, const int* __restrict__ rangeA,
    int* __restrict__ rangeCnt, int2* __restrict__ tmpE)
{
  __shared__ int cnt[kNRanges];
  __shared__ int lofs[kNRanges];
  __shared__ int gbase[kNRanges];
  __shared__ int wsum[16];
  __shared__ int2 sbuf[kSub];
  __shared__ unsigned short grg[kSub];
  const int tid  = threadIdx.x;
  const int lane = tid & 63;
  const int wid  = tid >> 6;
  const int e0   = blockIdx.x * kEdgesPerBin;
  int e1 = e0 + kEdgesPerBin;
  if (e1 > kNEdges) e1 = kNEdges;

  for (int sb = e0; sb < e1; sb += kSub) {
    const int n = min(kSub, e1 - sb);
    for (int g = tid; g < kNRanges; g += 1024) cnt[g] = 0;
    __syncthreads();

    // load + histogram; rank comes from the same LDS atomic
    int  myg[4], myrank[4];
    int2 myrec[4];
#pragma unroll
    for (int k = 0; k < 4; ++k) {
      const int i = k * 1024 + tid;
      myg[k] = -1;
      if (i < n) {
        const int e = sb + i;
        const int r = rows[e];
        const int g = r >> kRngShift;
        myg[k]    = g;
        myrank[k] = atomicAdd(&cnt[g], 1);
        myrec[k]  = make_int2(cols[e] | ((r & 255) << 18),
                              __float_as_int(vals[e]));
      }
    }
    __syncthreads();

    // exclusive scan of cnt[0..585] -> lofs; reserve global bursts
    const int c = (tid < kNRanges) ? cnt[tid] : 0;
    int v = c;
#pragma unroll
    for (int off = 1; off < 64; off <<= 1) {
      const int x = __shfl_up(v, off, 64);
      if (lane >= off) v += x;
    }
    if (lane == 63) wsum[wid] = v;
    __syncthreads();
    if (tid == 0) {
      int s = 0;
#pragma unroll
      for (int w = 0; w < 16; ++w) { const int t = wsum[w]; wsum[w] = s; s += t; }
    }
    __syncthreads();
    if (tid < kNRanges) {
      const int excl = wsum[wid] + v - c;
      lofs[tid] = excl;
      gbase[tid] = (c > 0) ? (rangeA[tid] + atomicAdd(&rangeCnt[tid], c)) : 0;
    }
    __syncthreads();

    // scatter into sorted LDS buffer
#pragma unroll
    for (int k = 0; k < 4; ++k) {
      if (myg[k] >= 0) {
        const int slot = lofs[myg[k]] + myrank[k];
        sbuf[slot] = myrec[k];
        grg[slot]  = (unsigned short)myg[k];
      }
    }
    __syncthreads();

    // ordered copy-out: consecutive t -> consecutive dst within each burst
    for (int t = tid; t < n; t += 1024) {
      const int g = grg[t];
      tmpE[gbase[g] + (t - lofs[g])] = sbuf[t];
    }
    __syncthreads();
  }
}

// One WG per range: derive local per-row CSR (LDS hist + block scan over the
// L2-resident slab), write rowPtr for its 256 rows, then place each edge at
// its exact CSR slot.
__global__ __launch_bounds__(256) void place_edges(
    const int2* __restrict__ tmpE, const int* __restrict__ rangeA,
    int2* __restrict__ edgeS, int* __restrict__ rowPtr)
{
  __shared__ int lcnt[256];
  __shared__ int lbase[256];
  __shared__ int ws[4];
  const int b    = blockIdx.x;
  const int r0   = b << kRngShift;
  const int tid  = threadIdx.x;
  const int lane = tid & 63;
  const int wid  = tid >> 6;
  const int start = rangeA[b];
  const int end   = rangeA[b + 1];

  lcnt[tid] = 0;
  __syncthreads();
  for (int e = start + tid; e < end; e += 256)
    atomicAdd(&lcnt[(tmpE[e].x >> 18) & 255], 1);
  __syncthreads();

  const int c = lcnt[tid];
  int v = c;
#pragma unroll
  for (int off = 1; off < 64; off <<= 1) {
    const int n = __shfl_up(v, off, 64);
    if (lane >= off) v += n;
  }
  if (lane == 63) ws[wid] = v;
  __syncthreads();
  int wadd = 0;
#pragma unroll
  for (int w = 0; w < 4; ++w) if (w < wid) wadd += ws[w];
  const int excl = v - c + wadd;
  lbase[tid] = start + excl;
  if (r0 + tid < kNNodes) rowPtr[r0 + tid] = start + excl;
  lcnt[tid] = 0;
  __syncthreads();

  for (int e = start + tid; e < end; e += 256) {
    const int2 cv = tmpE[e];
    const int rl  = (cv.x >> 18) & 255;
    const int rank = atomicAdd(&lcnt[rl], 1);
    edgeS[lbase[rl] + rank] = make_int2(cv.x & 0x3FFFF, cv.y);
  }
}

// ---------------------------------------------------------------------------
// CSR SpMM, bf16 gather, FUSED with t = n@W2 + b2.
// Edge loop: 8-wide unroll, 8 independent accumulators -> 8 gathers in
// flight per wave (was 4). Epilogue: 4 independent FMA chains.
// ---------------------------------------------------------------------------
__global__ __launch_bounds__(256) void spmm_csr16f(
    const unsigned short* __restrict__ cur16, const int* __restrict__ rowPtr,
    const int2* __restrict__ edgeS, const float* __restrict__ W2,
    const float* __restrict__ b2, float* __restrict__ nbuf)
{
  const int lane = threadIdx.x & 63;
  const int r = (blockIdx.x << 2) | (threadIdx.x >> 6);
  if (r >= kNNodes) return;
  const int start = __builtin_amdgcn_readfirstlane(rowPtr[r]);
  const int end   = __builtin_amdgcn_readfirstlane(rowPtr[r + 1]);
  float a0 = 0.f, a1 = 0.f, a2 = 0.f, a3 = 0.f;
  float a4 = 0.f, a5 = 0.f, a6 = 0.f, a7 = 0.f;
  int e = start;
  for (; e + 8 <= end; e += 8) {
    const int2 cv0 = edgeS[e];
    const int2 cv1 = edgeS[e + 1];
    const int2 cv2 = edgeS[e + 2];
    const int2 cv3 = edgeS[e + 3];
    const int2 cv4 = edgeS[e + 4];
    const int2 cv5 = edgeS[e + 5];
    const int2 cv6 = edgeS[e + 6];
    const int2 cv7 = edgeS[e + 7];
    const unsigned short u0 = cur16[(size_t)cv0.x * EMB + lane];
    const unsigned short u1 = cur16[(size_t)cv1.x * EMB + lane];
    const unsigned short u2 = cur16[(size_t)cv2.x * EMB + lane];
    const unsigned short u3 = cur16[(size_t)cv3.x * EMB + lane];
    const unsigned short u4 = cur16[(size_t)cv4.x * EMB + lane];
    const unsigned short u5 = cur16[(size_t)cv5.x * EMB + lane];
    const unsigned short u6 = cur16[(size_t)cv6.x * EMB + lane];
    const unsigned short u7 = cur16[(size_t)cv7.x * EMB + lane];
    a0 = fmaf(__int_as_float(cv0.y), bf2f(u0), a0);
    a1 = fmaf(__int_as_float(cv1.y), bf2f(u1), a1);
    a2 = fmaf(__int_as_float(cv2.y), bf2f(u2), a2);
    a3 = fmaf(__int_as_float(cv3.y), bf2f(u3), a3);
    a4 = fmaf(__int_as_float(cv4.y), bf2f(u4), a4);
    a5 = fmaf(__int_as_float(cv5.y), bf2f(u5), a5);
    a6 = fmaf(__int_as_float(cv6.y), bf2f(u6), a6);
    a7 = fmaf(__int_as_float(cv7.y), bf2f(u7), a7);
  }
  for (; e + 4 <= end; e += 4) {
    const int2 cv0 = edgeS[e];
    const int2 cv1 = edgeS[e + 1];
    const int2 cv2 = edgeS[e + 2];
    const int2 cv3 = edgeS[e + 3];
    const unsigned short u0 = cur16[(size_t)cv0.x * EMB + lane];
    const unsigned short u1 = cur16[(size_t)cv1.x * EMB + lane];
    const unsigned short u2 = cur16[(size_t)cv2.x * EMB + lane];
    const unsigned short u3 = cur16[(size_t)cv3.x * EMB + lane];
    a0 = fmaf(__int_as_float(cv0.y), bf2f(u0), a0);
    a1 = fmaf(__int_as_float(cv1.y), bf2f(u1), a1);
    a2 = fmaf(__int_as_float(cv2.y), bf2f(u2), a2);
    a3 = fmaf(__int_as_float(cv3.y), bf2f(u3), a3);
  }
  for (; e < end; ++e) {
    const int2 cv = edgeS[e];
    a0 = fmaf(__int_as_float(cv.y), bf2f(cur16[(size_t)cv.x * EMB + lane]), a0);
  }
  const float nsum = ((a0 + a4) + (a1 + a5)) + ((a2 + a6) + (a3 + a7));

  float t0 = b2[lane], t1 = 0.f, t2 = 0.f, t3 = 0.f;
#pragma unroll
  for (int k = 0; k < 64; k += 4) {
    const float nk0 = __shfl(nsum, k,     64);   // compile-time -> v_readlane
    const float nk1 = __shfl(nsum, k + 1, 64);
    const float nk2 = __shfl(nsum, k + 2, 64);
    const float nk3 = __shfl(nsum, k + 3, 64);
    t0 = fmaf(nk0, W2[(k    ) * EMB + lane], t0);
    t1 = fmaf(nk1, W2[(k + 1) * EMB + lane], t1);
    t2 = fmaf(nk2, W2[(k + 2) * EMB + lane], t2);
    t3 = fmaf(nk3, W2[(k + 3) * EMB + lane], t3);
  }
  nbuf[(size_t)r * EMB + lane] = (t0 + t1) + (t2 + t3);
}

// fp32-gather variant (fallback when ws can't hold cur16) — unfused.
__global__ __launch_bounds__(256) void spmm_csr(
    const float* __restrict__ cur, const int* __restrict__ rowPtr,
    const int2* __restrict__ edgeS, float* __restrict__ nbuf)
{
  const int lane = threadIdx.x & 63;
  const int r = (blockIdx.x << 2) | (threadIdx.x >> 6);
  if (r >= kNNodes) return;
  const int start = __builtin_amdgcn_readfirstlane(rowPtr[r]);
  const int end   = __builtin_amdgcn_readfirstlane(rowPtr[r + 1]);
  float a0 = 0.f, a1 = 0.f, a2 = 0.f, a3 = 0.f;
  int e = start;
  for (; e + 4 <= end; e += 4) {
    const int2 cv0 = edgeS[e];
    const int2 cv1 = edgeS[e + 1];
    const int2 cv2 = edgeS[e + 2];
    const int2 cv3 = edgeS[e + 3];
    a0 = fmaf(__int_as_float(cv0.y), cur[(size_t)cv0.x * EMB + lane], a0);
    a1 = fmaf(__int_as_float(cv1.y), cur[(size_t)cv1.x * EMB + lane], a1);
    a2 = fmaf(__int_as_float(cv2.y), cur[(size_t)cv2.x * EMB + lane], a2);
    a3 = fmaf(__int_as_float(cv3.y), cur[(size_t)cv3.x * EMB + lane], a3);
  }
  for (; e < end; ++e) {
    const int2 cv = edgeS[e];
    a0 = fmaf(__int_as_float(cv.y), cur[(size_t)cv.x * EMB + lane], a0);
  }
  nbuf[(size_t)r * EMB + lane] = (a0 + a1) + (a2 + a3);
}

__global__ __launch_bounds__(256) void spmm_atomic(
    const float* __restrict__ cur, const int* __restrict__ rows,
    const int* __restrict__ cols, const float* __restrict__ vals,
    float* __restrict__ nbuf)
{
  const int lane = threadIdx.x & 63;
  int wv = (blockIdx.x << 2) | (threadIdx.x >> 6);
  wv = __builtin_amdgcn_readfirstlane(wv);
  int e0 = wv * kEPW;
  int e1 = e0 + kEPW;
  if (e1 > kNEdges) e1 = kNEdges;
  for (int e = e0; e < e1; ++e) {
    atomicAdd(nbuf + (size_t)rows[e] * EMB + lane,
              vals[e] * cur[(size_t)cols[e] * EMB + lane]);
  }
}

// ---------------------------------------------------------------------------
// Fallback-only: t = n@W2 + b2, in place over nbuf (for the non-CSR path).
// ---------------------------------------------------------------------------
__global__ __launch_bounds__(256) void transform_nbr(
    float* __restrict__ nbuf, const float* __restrict__ W2,
    const float* __restrict__ b2)
{
  const int node = blockIdx.x * 256 + threadIdx.x;
  if (node >= kNNodes) return;
  const float4* __restrict__ nr  = (const float4*)(nbuf + (size_t)node * EMB);
  const float4* __restrict__ b2v = (const float4*)b2;
#define DECL(j) float4 a##j = b2v[j];
  F16(DECL)
#undef DECL
#pragma unroll 4
  for (int k4 = 0; k4 < 16; ++k4) {
    const float4 nv = nr[k4];
#pragma unroll
    for (int kk = 0; kk < 4; ++kk) {
      const float ns = f4c(nv, kk);
      const float4* __restrict__ w2r = (const float4*)(W2 + (4 * k4 + kk) * EMB);
#define STEP(j) a##j = f4fma(ns, w2r[j], a##j);
      F16(STEP)
#undef STEP
    }
  }
  float4* __restrict__ outp = (float4*)(nbuf + (size_t)node * EMB);
#define STORE(j) outp[j] = a##j;
  F16(STORE)
#undef STORE
}

// ---------------------------------------------------------------------------
// Transform pass 2: cur = lrelu(x@W1 + b1 + b2 + (t*x)@W2 + t), t from nbuf.
// ---------------------------------------------------------------------------
__global__ __launch_bounds__(256) void transform_self(
    float* __restrict__ cur, const float* __restrict__ nbuf,
    const float* __restrict__ W1, const float* __restrict__ b1,
    const float* __restrict__ b2, const float* __restrict__ W2)
{
  const int node = blockIdx.x * 256 + threadIdx.x;
  if (node >= kNNodes) return;
  const float4* __restrict__ xr  = (const float4*)(cur  + (size_t)node * EMB);
  const float4* __restrict__ tr  = (const float4*)(nbuf + (size_t)node * EMB);
  const float4* __restrict__ b1v = (const float4*)b1;
  const float4* __restrict__ b2v = (const float4*)b2;
#define DECL(j) float4 a##j = f4add(b1v[j], b2v[j]);
  F16(DECL)
#undef DECL
#pragma unroll 2
  for (int k4 = 0; k4 < 16; ++k4) {
    const float4 xv = xr[k4];
    const float4 tv = tr[k4];
#pragma unroll
    for (int kk = 0; kk < 4; ++kk) {
      const float xs = f4c(xv, kk);
      const float ms = f4c(tv, kk) * xs;
      const int k = 4 * k4 + kk;
      const float4* __restrict__ w1r = (const float4*)(W1 + k * EMB);
      const float4* __restrict__ w2r = (const float4*)(W2 + k * EMB);
#define STEP(j) a##j = f4fma(xs, w1r[j], a##j); a##j = f4fma(ms, w2r[j], a##j);
      F16(STEP)
#undef STEP
    }
  }
  float4* __restrict__ outp = (float4*)(cur + (size_t)node * EMB);
#define STORE(j) { const float4 tj = tr[j]; float4 r;          \
    r.x = lrelu(a##j.x + tj.x); r.y = lrelu(a##j.y + tj.y);    \
    r.z = lrelu(a##j.z + tj.z); r.w = lrelu(a##j.w + tj.w);    \
    outp[j] = r; }
  F16(STORE)
#undef STORE
}

// ---------------------------------------------------------------------------
__global__ __launch_bounds__(256) void gather_out(
    const float* __restrict__ cur, const int* __restrict__ users,
    const int* __restrict__ pos, const int* __restrict__ neg,
    float* __restrict__ out, int layer)
{
  const int t    = blockIdx.x * 256 + threadIdx.x;
  const int lane = t & 63;
  const int rid  = t >> 6;
  if (rid >= 3 * kBatch) return;
  const int seg = rid / kBatch;
  const int b   = rid - seg * kBatch;
  int idx;
  if (seg == 0)      idx = users[b];
  else if (seg == 1) idx = pos[b] + kNUsers;
  else               idx = neg[b] + kNUsers;
  out[(size_t)rid * 256 + layer * EMB + lane] = cur[(size_t)idx * EMB + lane];
}

// ---------------------------------------------------------------------------
extern "C" void kernel_launch(void* const* d_in, const int* in_sizes, int n_in,
                              void* d_out, int out_size, void* d_ws, size_t ws_size,
                              hipStream_t stream) {
  const int*   users    = (const int*)d_in[0];
  const int*   pos      = (const int*)d_in[1];
  const int*   neg      = (const int*)d_in[2];
  const int*   rows     = (const int*)d_in[3];
  const int*   cols     = (const int*)d_in[4];
  const float* vals     = (const float*)d_in[5];
  const float* user_emb = (const float*)d_in[6];
  const float* item_emb = (const float*)d_in[7];
  const float* W1s      = (const float*)d_in[8];
  const float* b1s      = (const float*)d_in[9];
  const float* W2s      = (const float*)d_in[10];
  const float* b2s      = (const float*)d_in[11];
  float* out = (float*)d_out;

  const size_t nodeF = (size_t)kNNodes * EMB;
  float* cur  = (float*)d_ws;                               // 38.4 MB
  float* nbuf = cur + nodeF;                                // 38.4 MB (tmpE alias)
  int2*  edgeS     = (int2*)(nbuf + nodeF);                 // 38.4 MB
  int*   rowPtr    = (int*)(edgeS + kNEdges);               // 600 KB (+1)
  int*   rangeA    = rowPtr + (kNNodes + 1);                // 2.3 KB (+1)
  int*   rangeCnt  = rangeA + (kNRanges + 1);               // 2.3 KB
  unsigned short* cur16 = (unsigned short*)(rangeCnt + kNRanges);  // 19.2 MB
  int2*  tmpE = (int2*)nbuf;                                // binned records
  const size_t neededCsr = (size_t)((char*)cur16 - (char*)d_ws);
  const size_t needed16  = neededCsr + nodeF * sizeof(unsigned short);
  const bool useCsr = ws_size >= neededCsr;
  const bool use16  = useCsr && ws_size >= needed16;

  const dim3 blk(256);
  const int iblocks = (int)((nodeF / 4 + 255) / 256);       // 9375
  const int gblocks = (3 * kBatch * EMB + 255) / 256;       // 12288
  const int rblocks = (kNNodes + 3) / 4;                    // 37500
  const int tblocks = (kNNodes + 255) / 256;                // 586

  init_embed<<<iblocks, blk, 0, stream>>>(user_emb, item_emb, cur, cur16,
                                          use16 ? 1 : 0);

  if (useCsr) {
    // zero rangeA (totals) + rangeCnt (burst frontiers) — contiguous
    hipMemsetAsync(rangeA, 0, (size_t)(2 * kNRanges + 1) * sizeof(int), stream);
    hist_ranges<<<kBinBlocks, dim3(1024), 0, stream>>>(rows, rangeA);
    scan_ranges<<<1, 1024, 0, stream>>>(rangeA, rowPtr);
    bin_edges<<<kBinBlocks, dim3(1024), 0, stream>>>(rows, cols, vals, rangeA,
                                                     rangeCnt, tmpE);
    place_edges<<<kNRanges, blk, 0, stream>>>(tmpE, rangeA, edgeS, rowPtr);
  }

  gather_out<<<gblocks, blk, 0, stream>>>(cur, users, pos, neg, out, 0);

  for (int L = 0; L < kLayers; ++L) {
    const float* W1 = W1s + L * EMB * EMB;
    const float* b1 = b1s + L * EMB;
    const float* W2 = W2s + L * EMB * EMB;
    const float* b2 = b2s + L * EMB;
    if (useCsr && use16) {
      // fused: nbuf <- t = (A @ cur) @ W2 + b2
      spmm_csr16f<<<rblocks, blk, 0, stream>>>(cur16, rowPtr, edgeS, W2, b2,
                                               nbuf);
    } else if (useCsr) {
      spmm_csr<<<rblocks, blk, 0, stream>>>(cur, rowPtr, edgeS, nbuf);
      transform_nbr<<<tblocks, blk, 0, stream>>>(nbuf, W2, b2);
    } else {
      hipMemsetAsync(nbuf, 0, nodeF * sizeof(float), stream);
      const int sblocks = (((kNEdges + kEPW - 1) / kEPW) + 3) / 4;
      spmm_atomic<<<sblocks, blk, 0, stream>>>(cur, rows, cols, vals, nbuf);
      transform_nbr<<<tblocks, blk, 0, stream>>>(nbuf, W2, b2);
    }
    transform_self<<<tblocks, blk, 0, stream>>>(cur, nbuf, W1, b1, b2, W2);
    if (use16 && L + 1 < kLayers)
      refresh16<<<iblocks, blk, 0, stream>>>(cur, cur16);
    gather_out<<<gblocks, blk, 0, stream>>>(cur, users, pos, neg, out, L + 1);
  }
}